// Round 5
// baseline (332.552 us; speedup 1.0000x reference)
//
#include <hip/hip_runtime.h>
#include <hip/hip_fp16.h>

#define IRR    56
#define EF     48
#define WN     832
#define NEDGE  160000
#define NNODE  8000
#define NT     512                // 8 waves: crew0 (waves 0-3) flavor 0, crew1 (waves 4-7) flavor 1
#define TE2    64                 // edges per block
#define NTASK  (NEDGE / TE2)      // 2500
#define GRID   NTASK

#define INV_SQRT3 0.5773502691896258f
#define INV_SQRT2 0.7071067811865476f
#define A_SCAL    0.22360679774997896f   // 1/sqrt(20)
#define A_VEC     0.20412414523193154f   // 1/sqrt(24)

typedef __bf16 bf16x8 __attribute__((ext_vector_type(8)));
typedef float  f32x4  __attribute__((ext_vector_type(4)));
typedef unsigned short u16x8 __attribute__((ext_vector_type(8)));
typedef unsigned short u16x4 __attribute__((ext_vector_type(4)));

__device__ __forceinline__ unsigned short f2bf(float f) {
    unsigned int u = __builtin_bit_cast(unsigned int, f);
    u += 0x7FFFu + ((u >> 16) & 1u);          // RNE
    return (unsigned short)(u >> 16);
}

// ---- setup: W1T [n][64] + W2L lane-major fragment layout + src histogram ----
// W2L[o]: o = ((i*2+f)*64 + l)*8 + j ; lane l=(q*16+m); value = W2[k= f*32+q*8+j][n= i*16+m]
__global__ void k_setup(const float* __restrict__ w1, const float* __restrict__ b1,
                        const float* __restrict__ w2, const float* __restrict__ b2,
                        unsigned short* __restrict__ W1T, unsigned short* __restrict__ W2L,
                        const int* __restrict__ edge_index, int* __restrict__ hist)
{
    int o = blockIdx.x * 256 + threadIdx.x;
    if (o < 64 * 832) {                       // 53248 elements, coalesced over n
        int k = o / 832;
        int n = o - k * 832;
        float v = (k < EF) ? w2[k * WN + n] : ((k == EF) ? b2[n] : 0.f);
        int i = n >> 4, mm = n & 15;
        int f = k >> 5, q = (k >> 3) & 3, j = k & 7;
        int o2 = (((i * 2 + f) * 64) + (q * 16 + mm)) * 8 + j;
        W2L[o2] = f2bf(v);
    }
    if (o < EF * EF) { int k = o / EF, n = o - k * EF; W1T[n * 64 + k] = f2bf(w1[o]); }
    if (o < EF * 16) { int n = o >> 4, kk = EF + (o & 15); W1T[n * 64 + kk] = (kk == EF) ? f2bf(b1[n]) : (unsigned short)0; }
    if (o < NEDGE) atomicAdd(&hist[edge_index[o]], 1);   // src counts
}

__global__ __launch_bounds__(NT, 4) void tp_fused(
    const float* __restrict__ node_attr,
    const float* __restrict__ edge_attr,
    const float* __restrict__ edge_sh,
    const int*   __restrict__ edge_index,
    const int*   __restrict__ hist,
    const unsigned short* __restrict__ W1T,
    const unsigned short* __restrict__ W2L,
    float* __restrict__ out)
{
    // 55.5 KB LDS -> 2 blocks/CU (16 waves); VGPR cap 128 via launch_bounds(512,4).
    __shared__ __align__(16) float sG[TE2 * 56];               // 14336 B gathered node rows
    __shared__ __align__(16) unsigned short sH[TE2 * 72];      // 9216 B  H (bf16), stride 72 for bank spread
    __shared__ __align__(16) float sF0[TE2 * 61];              // 15616 B flavor-0 features (stride 61: indices 0..59 used)
    __shared__ __align__(16) float sF1[TE2 * 61];              // 15616 B flavor-1 features
    __shared__ int   sSrc[TE2], sDst[TE2];
    __shared__ float sInv[TE2];

    const int tid   = threadIdx.x;
    const int lane  = tid & 63;
    const int wv    = tid >> 6;                  // 0..7
    const int half  = wv >> 2;                   // crew: 0 -> flavor 0, 1 -> flavor 1
    const int wl    = wv & 3;                    // wave within crew
    const int m     = lane & 15;
    const int quad  = lane >> 4;
    const int em    = wl * 16 + m;               // block-local edge owned by this lane (per crew)
    const int e0    = blockIdx.x * TE2;

    if (tid < TE2)          sSrc[tid]       = edge_index[e0 + tid];
    else if (tid < 2 * TE2) sDst[tid - TE2] = edge_index[NEDGE + e0 + tid - TE2];
    __syncthreads();   // (A) sSrc/sDst visible

    // ---- gather node rows: split across all 8 waves (crew0 cols 0-7, crew1 cols 8-13) ----
    {
        const float* nrow = node_attr + (size_t)sDst[em] * IRR;
        float* g = sG + em * 56;
        if (half == 0) {
            *(float4*)(g + quad * 4)        = *(const float4*)(nrow + quad * 4);
            *(float4*)(g + (quad + 4) * 4)  = *(const float4*)(nrow + (quad + 4) * 4);
        } else {
            *(float4*)(g + (quad + 8) * 4)  = *(const float4*)(nrow + (quad + 8) * 4);
            if (quad < 2) { int c = 12 + quad; *(float4*)(g + c * 4) = *(const float4*)(nrow + c * 4); }
        }
    }
    if (tid >= 256 && tid < 256 + TE2) {         // crew1 wave 0 computes inv counts
        int e = tid - 256;
        sInv[e] = 1.0f / fmaxf((float)hist[sSrc[e]], 1.0f);
    }

    // edge_sh kept in registers (each lane holds its em's values)
    float4 sh4 = *(const float4*)&edge_sh[(size_t)(e0 + em) * 4];
    const float s0 = sh4.x, sx = sh4.y, sy = sh4.z, sz = sh4.w;

    __syncthreads();   // (B) sG complete

    // ---- F features in f32: crew0 builds F0, crew1 builds F1 (wave-local rows, no barrier) ----
    {
        const float* x = sG + em * 56;
        const float c0S = s0 * A_SCAL;
        const float c0V = s0 * A_VEC;
        const float cD3 = INV_SQRT3 * A_SCAL;
        const float cC2 = INV_SQRT2 * A_VEC;
        if (half == 0) {
            float* F = sF0 + em * 61;
            #pragma unroll
            for (int t = 0; t < 4; t++) {
                int u = quad * 4 + t;
                float x0e = x[u];
                F[u]      = x0e * c0S;    // wA0
                F[20 + u] = x0e * A_VEC;  // wA1
            }
            {
                int u = quad;
                float a0 = x[16 + u*3], a1 = x[16 + u*3 + 1], a2 = x[16 + u*3 + 2]; // x1o
                float b0 = x[28 + u*3], b1 = x[28 + u*3 + 1], b2 = x[28 + u*3 + 2]; // x1e
                F[16 + u] = (a0*sx + a1*sy + a2*sz) * cD3;        // wB0 dot_b
                F[36 + u*3 + 0] = a0 * c0V;                       // wB1
                F[36 + u*3 + 1] = a1 * c0V;
                F[36 + u*3 + 2] = a2 * c0V;
                F[48 + u*3 + 0] = (b1*sz - b2*sy) * cC2;          // wC1 cross(x1e,s1)  [..59]
                F[48 + u*3 + 1] = (b2*sx - b0*sz) * cC2;
                F[48 + u*3 + 2] = (b0*sy - b1*sx) * cC2;
            }
        } else {
            float* F = sF1 + em * 61;
            {
                int u = quad;
                float a0 = x[16 + u*3], a1 = x[16 + u*3 + 1], a2 = x[16 + u*3 + 2]; // x1o
                float b0 = x[28 + u*3], b1 = x[28 + u*3 + 1], b2 = x[28 + u*3 + 2]; // x1e
                F[u*3 + 0]      = (a1*sz - a2*sy) * cC2;          // wB1e cross(x1o,s1)
                F[u*3 + 1]      = (a2*sx - a0*sz) * cC2;
                F[u*3 + 2]      = (a0*sy - a1*sx) * cC2;
                F[12 + u*3 + 0] = b0 * c0V;                       // wC1e
                F[12 + u*3 + 1] = b1 * c0V;
                F[12 + u*3 + 2] = b2 * c0V;
                F[40 + u]       = (b0*sx + b1*sy + b2*sz) * cD3;  // wC0o dot_c
            }
            #pragma unroll
            for (int t = 0; t < 4; t++) {
                int u = quad * 4 + t;
                float x0o = x[40 + u];
                F[24 + u] = x0o * A_VEC;  // wD1e
                F[44 + u] = x0o * c0S;    // wD0o  [..59]
            }
        }
    }

    const unsigned short* Wt = W2L + (size_t)half * 26 * 1024;  // this crew's 26 tiles (L2-hot)

    // ---- crew0 preloads edge_attr -> bf16 regs + GEMM1 ----
    bf16x8 hb0, hb1;
    if (half == 0) {
        const float* arow = edge_attr + (size_t)(e0 + em) * EF;
        float av0[8], av1[8];
        {
            float4 p0 = *(const float4*)(arow + quad * 8);
            float4 p1 = *(const float4*)(arow + quad * 8 + 4);
            av0[0]=p0.x; av0[1]=p0.y; av0[2]=p0.z; av0[3]=p0.w;
            av0[4]=p1.x; av0[5]=p1.y; av0[6]=p1.z; av0[7]=p1.w;
        }
        if (quad < 2) {
            float4 p0 = *(const float4*)(arow + 32 + quad * 8);
            float4 p1 = *(const float4*)(arow + 32 + quad * 8 + 4);
            av1[0]=p0.x; av1[1]=p0.y; av1[2]=p0.z; av1[3]=p0.w;
            av1[4]=p1.x; av1[5]=p1.y; av1[6]=p1.z; av1[7]=p1.w;
        } else {
            #pragma unroll
            for (int j = 0; j < 8; j++) av1[j] = 0.f;
            if (quad == 2) av1[0] = 1.f;           // bias row k=48
        }
        u16x8 ub0, ub1;
        #pragma unroll
        for (int j = 0; j < 8; j++) { ub0[j] = f2bf(av0[j]); ub1[j] = f2bf(av1[j]); }
        hb0 = __builtin_bit_cast(bf16x8, ub0);
        hb1 = __builtin_bit_cast(bf16x8, ub1);

        // ---- GEMM1 (crew0 only): H[e][hid] -> sH ----
        #pragma unroll
        for (int nth = 0; nth < 3; nth++) {
            bf16x8 a0 = __builtin_bit_cast(bf16x8, *(const u16x8*)&W1T[(nth*16 + m)*64 + quad*8]);
            bf16x8 a1 = __builtin_bit_cast(bf16x8, *(const u16x8*)&W1T[(nth*16 + m)*64 + 32 + quad*8]);
            f32x4 c = {0.f, 0.f, 0.f, 0.f};
            c = __builtin_amdgcn_mfma_f32_16x16x32_bf16(a0, hb0, c, 0, 0, 0);
            c = __builtin_amdgcn_mfma_f32_16x16x32_bf16(a1, hb1, c, 0, 0, 0);
            u16x4 hp;
            #pragma unroll
            for (int r = 0; r < 4; r++) hp[r] = f2bf(fmaxf(c[r], 0.f));
            *(u16x4*)&sH[em * 72 + nth*16 + quad*4] = hp;
        }
        if (quad == 3) {
            u16x4 b = {0x3F80, 0, 0, 0}, z = {0, 0, 0, 0};
            *(u16x4*)&sH[em * 72 + 48] = b;
            *(u16x4*)&sH[em * 72 + 52] = z;
            *(u16x4*)&sH[em * 72 + 56] = z;
            *(u16x4*)&sH[em * 72 + 60] = z;
        }
    }

    // ---- prime the W2 register ring (8 tiles deep, 16 loads in flight) ----
    // Independent of LDS; latency overlaps barrier (D).
    u16x8 AFr[8], BFr[8];
    #pragma unroll
    for (int p = 0; p < 8; p++) {
        AFr[p] = *(const u16x8*)&Wt[p * 1024 + lane * 8];
        BFr[p] = *(const u16x8*)&Wt[p * 1024 + 512 + lane * 8];
    }

    __syncthreads();   // (D) sH visible to all waves

    bf16x8 HB0 = __builtin_bit_cast(bf16x8, *(const u16x8*)&sH[em * 72 + quad*8]);
    bf16x8 HB1 = __builtin_bit_cast(bf16x8, *(const u16x8*)&sH[em * 72 + 32 + quad*8]);
    const float inv = sInv[em];
    float* orow = out + (size_t)sSrc[em] * IRR;

    if (half == 0) {
        const float* Fp = sF0 + em * 61;
        // ---- tiles 0..25: o0e (ch 0..15) + o1o (ch 16..27) ----
        float oe[4] = {0.f,0.f,0.f,0.f};
        float sA[4] = {0.f,0.f,0.f,0.f};
        float t1[12] = {0.f,0.f,0.f,0.f,0.f,0.f,0.f,0.f,0.f,0.f,0.f,0.f};
        #pragma unroll
        for (int i = 0; i < 26; i++) {
            u16x8 Af = AFr[i & 7];
            u16x8 Bf = BFr[i & 7];
            if (i + 8 < 26) {       // refill ring slot with tile i+8 (static idx under unroll)
                AFr[i & 7] = *(const u16x8*)&Wt[(i + 8) * 1024 + lane * 8];
                BFr[i & 7] = *(const u16x8*)&Wt[(i + 8) * 1024 + 512 + lane * 8];
            }
            f32x4 c = {0.f,0.f,0.f,0.f};
            c = __builtin_amdgcn_mfma_f32_16x16x32_bf16(__builtin_bit_cast(bf16x8, Af), HB0, c, 0, 0, 0);
            c = __builtin_amdgcn_mfma_f32_16x16x32_bf16(__builtin_bit_cast(bf16x8, Bf), HB1, c, 0, 0, 0);
            if (i < 20) {
                float f = Fp[i];
                #pragma unroll
                for (int r = 0; r < 4; r++) oe[r] += f * c[r];
            } else if (i < 24) {
                float f = Fp[20 + (i - 20)*4 + quad];
                #pragma unroll
                for (int r = 0; r < 4; r++) sA[r] += f * c[r];
            } else {
                int u = (i - 24)*4 + quad;
                #pragma unroll
                for (int i3 = 0; i3 < 3; i3++) {
                    float f = Fp[36 + u*3 + i3];
                    #pragma unroll
                    for (int r = 0; r < 4; r++) t1[i3*4 + r] += f * c[r];
                }
            }
        }
        #pragma unroll
        for (int r = 0; r < 4; r++) {
            sA[r] += __shfl_xor(sA[r], 16, 64);  sA[r] += __shfl_xor(sA[r], 32, 64);
        }
        #pragma unroll
        for (int i = 0; i < 12; i++) {
            t1[i] += __shfl_xor(t1[i], 16, 64);  t1[i] += __shfl_xor(t1[i], 32, 64);
        }
        // ---- direct atomic scatter from registers ----
        #pragma unroll
        for (int r = 0; r < 4; r++)
            unsafeAtomicAdd(&orow[quad*4 + r], oe[r] * inv);    // ch 0..15
        #pragma unroll
        for (int q = 0; q < 4; q++) if (quad == q) {            // ch 16..27 (quad q -> group q)
            unsafeAtomicAdd(&orow[16 + q*3 + 0], (sA[q]*sx + t1[0*4 + q]) * inv);
            unsafeAtomicAdd(&orow[16 + q*3 + 1], (sA[q]*sy + t1[1*4 + q]) * inv);
            unsafeAtomicAdd(&orow[16 + q*3 + 2], (sA[q]*sz + t1[2*4 + q]) * inv);
        }
    } else {
        const float* Fp = sF1 + em * 61;
        // ---- tiles 26..51: o1e (ch 28..39) + o0o (ch 40..55) ----
        float sD[4] = {0.f,0.f,0.f,0.f};
        float t1[12] = {0.f,0.f,0.f,0.f,0.f,0.f,0.f,0.f,0.f,0.f,0.f,0.f};
        float oo[4] = {0.f,0.f,0.f,0.f};
        #pragma unroll
        for (int i = 0; i < 26; i++) {
            u16x8 Af = AFr[i & 7];
            u16x8 Bf = BFr[i & 7];
            if (i + 8 < 26) {
                AFr[i & 7] = *(const u16x8*)&Wt[(i + 8) * 1024 + lane * 8];
                BFr[i & 7] = *(const u16x8*)&Wt[(i + 8) * 1024 + 512 + lane * 8];
            }
            f32x4 c = {0.f,0.f,0.f,0.f};
            c = __builtin_amdgcn_mfma_f32_16x16x32_bf16(__builtin_bit_cast(bf16x8, Af), HB0, c, 0, 0, 0);
            c = __builtin_amdgcn_mfma_f32_16x16x32_bf16(__builtin_bit_cast(bf16x8, Bf), HB1, c, 0, 0, 0);
            if (i < 2) {
                int j = i*4 + quad;
                #pragma unroll
                for (int i3 = 0; i3 < 3; i3++) {
                    float f = Fp[j*3 + i3];
                    #pragma unroll
                    for (int r = 0; r < 4; r++) t1[i3*4 + r] += f * c[r];
                }
            } else if (i < 6) {
                float f = Fp[24 + (i - 2)*4 + quad];
                #pragma unroll
                for (int r = 0; r < 4; r++) sD[r] += f * c[r];
            } else {
                float f = Fp[40 + (i - 6)];
                #pragma unroll
                for (int r = 0; r < 4; r++) oo[r] += f * c[r];
            }
        }
        #pragma unroll
        for (int r = 0; r < 4; r++) {
            sD[r] += __shfl_xor(sD[r], 16, 64);  sD[r] += __shfl_xor(sD[r], 32, 64);
        }
        #pragma unroll
        for (int i = 0; i < 12; i++) {
            t1[i] += __shfl_xor(t1[i], 16, 64);  t1[i] += __shfl_xor(t1[i], 32, 64);
        }
        #pragma unroll
        for (int r = 0; r < 4; r++)
            unsafeAtomicAdd(&orow[40 + quad*4 + r], oo[r] * inv);   // ch 40..55
        #pragma unroll
        for (int q = 0; q < 4; q++) if (quad == q) {                // ch 28..39
            unsafeAtomicAdd(&orow[28 + q*3 + 0], (sD[q]*sx + t1[0*4 + q]) * inv);
            unsafeAtomicAdd(&orow[28 + q*3 + 1], (sD[q]*sy + t1[1*4 + q]) * inv);
            unsafeAtomicAdd(&orow[28 + q*3 + 2], (sD[q]*sz + t1[2*4 + q]) * inv);
        }
    }
}

extern "C" void kernel_launch(void* const* d_in, const int* in_sizes, int n_in,
                              void* d_out, int out_size, void* d_ws, size_t ws_size,
                              hipStream_t stream) {
    const float* node_attr  = (const float*)d_in[0];
    const float* edge_attr  = (const float*)d_in[1];
    const float* edge_sh    = (const float*)d_in[2];
    const float* fc_w1      = (const float*)d_in[3];
    const float* fc_b1      = (const float*)d_in[4];
    const float* fc_w2      = (const float*)d_in[5];
    const float* fc_b2      = (const float*)d_in[6];
    const int*   edge_index = (const int*)d_in[7];

    int* hist = (int*)d_ws;                                    // 8000 ints
    unsigned short* W1T = (unsigned short*)(hist + NNODE);     // 48*64
    unsigned short* W2L = W1T + EF * 64;                       // 52*2*64*8 = 53248

    hipMemsetAsync(hist, 0, NNODE * sizeof(int), stream);
    hipMemsetAsync(d_out, 0, (size_t)out_size * sizeof(float), stream);

    k_setup<<<(NEDGE + 255) / 256, 256, 0, stream>>>(
        fc_w1, fc_b1, fc_w2, fc_b2, W1T, W2L, edge_index, hist);

    tp_fused<<<GRID, NT, 0, stream>>>(node_attr, edge_attr, edge_sh, edge_index,
                                      hist, W1T, W2L, (float*)d_out);
}

// Round 6
// 324.560 us; speedup vs baseline: 1.0246x; 1.0246x over previous
//
#include <hip/hip_runtime.h>
#include <hip/hip_fp16.h>

#define IRR    56
#define EF     48
#define WN     832
#define NEDGE  160000
#define NNODE  8000
#define NT     512                // 8 waves: crew0 (waves 0-3) flavor 0, crew1 (waves 4-7) flavor 1
#define TE2    64                 // edges per block
#define NTASK  (NEDGE / TE2)      // 2500
#define GRID   NTASK

#define INV_SQRT3 0.5773502691896258f
#define INV_SQRT2 0.7071067811865476f
#define A_SCAL    0.22360679774997896f   // 1/sqrt(20)
#define A_VEC     0.20412414523193154f   // 1/sqrt(24)

typedef __bf16 bf16x8 __attribute__((ext_vector_type(8)));
typedef float  f32x4  __attribute__((ext_vector_type(4)));
typedef unsigned short u16x8 __attribute__((ext_vector_type(8)));
typedef unsigned short u16x4 __attribute__((ext_vector_type(4)));

__device__ __forceinline__ unsigned short f2bf(float f) {
    unsigned int u = __builtin_bit_cast(unsigned int, f);
    u += 0x7FFFu + ((u >> 16) & 1u);          // RNE
    return (unsigned short)(u >> 16);
}

// ---- setup: W1T [n][64] + W2L lane-major fragment layout + src histogram ----
// W2L[o]: o = ((i*2+f)*64 + l)*8 + j ; lane l=(q*16+m); value = W2[k= f*32+q*8+j][n= i*16+m]
__global__ void k_setup(const float* __restrict__ w1, const float* __restrict__ b1,
                        const float* __restrict__ w2, const float* __restrict__ b2,
                        unsigned short* __restrict__ W1T, unsigned short* __restrict__ W2L,
                        const int* __restrict__ edge_index, int* __restrict__ hist)
{
    int o = blockIdx.x * 256 + threadIdx.x;
    if (o < 64 * 832) {                       // 53248 elements, coalesced over n
        int k = o / 832;
        int n = o - k * 832;
        float v = (k < EF) ? w2[k * WN + n] : ((k == EF) ? b2[n] : 0.f);
        int i = n >> 4, mm = n & 15;
        int f = k >> 5, q = (k >> 3) & 3, j = k & 7;
        int o2 = (((i * 2 + f) * 64) + (q * 16 + mm)) * 8 + j;
        W2L[o2] = f2bf(v);
    }
    if (o < EF * EF) { int k = o / EF, n = o - k * EF; W1T[n * 64 + k] = f2bf(w1[o]); }
    if (o < EF * 16) { int n = o >> 4, kk = EF + (o & 15); W1T[n * 64 + kk] = (kk == EF) ? f2bf(b1[n]) : (unsigned short)0; }
    if (o < NEDGE) atomicAdd(&hist[edge_index[o]], 1);   // src counts
}

__global__ __launch_bounds__(NT, 2) void tp_fused(
    const float* __restrict__ node_attr,
    const float* __restrict__ edge_attr,
    const float* __restrict__ edge_sh,
    const int*   __restrict__ edge_index,
    const int*   __restrict__ hist,
    const unsigned short* __restrict__ W1T,
    const unsigned short* __restrict__ W2L,
    float* __restrict__ out)
{
    // 55.5 KB LDS -> 2 blocks/CU (16 waves). launch_bounds(512,2): under either
    // semantics (waves/EU or blocks/CU) this permits >=128 VGPRs -> ring stays in regs.
    __shared__ __align__(16) float sG[TE2 * 56];               // 14336 B gathered node rows
    __shared__ __align__(16) unsigned short sH[TE2 * 72];      // 9216 B  H (bf16), stride 72 for bank spread
    __shared__ __align__(16) float sF0[TE2 * 61];              // 15616 B flavor-0 features (indices 0..59 used)
    __shared__ __align__(16) float sF1[TE2 * 61];              // 15616 B flavor-1 features
    __shared__ int   sSrc[TE2], sDst[TE2];
    __shared__ float sInv[TE2];

    const int tid   = threadIdx.x;
    const int lane  = tid & 63;
    const int wv    = tid >> 6;                  // 0..7
    const int half  = wv >> 2;                   // crew: 0 -> flavor 0, 1 -> flavor 1
    const int wl    = wv & 3;                    // wave within crew
    const int m     = lane & 15;
    const int quad  = lane >> 4;
    const int em    = wl * 16 + m;               // block-local edge owned by this lane (per crew)
    const int e0    = blockIdx.x * TE2;

    if (tid < TE2)          sSrc[tid]       = edge_index[e0 + tid];
    else if (tid < 2 * TE2) sDst[tid - TE2] = edge_index[NEDGE + e0 + tid - TE2];
    __syncthreads();   // (A) sSrc/sDst visible

    // ---- gather node rows: split across all 8 waves (crew0 cols 0-7, crew1 cols 8-13) ----
    {
        const float* nrow = node_attr + (size_t)sDst[em] * IRR;
        float* g = sG + em * 56;
        if (half == 0) {
            *(float4*)(g + quad * 4)        = *(const float4*)(nrow + quad * 4);
            *(float4*)(g + (quad + 4) * 4)  = *(const float4*)(nrow + (quad + 4) * 4);
        } else {
            *(float4*)(g + (quad + 8) * 4)  = *(const float4*)(nrow + (quad + 8) * 4);
            if (quad < 2) { int c = 12 + quad; *(float4*)(g + c * 4) = *(const float4*)(nrow + c * 4); }
        }
    }
    if (tid >= 256 && tid < 256 + TE2) {         // crew1 wave 0 computes inv counts
        int e = tid - 256;
        sInv[e] = 1.0f / fmaxf((float)hist[sSrc[e]], 1.0f);
    }

    // edge_sh kept in registers (each lane holds its em's values)
    float4 sh4 = *(const float4*)&edge_sh[(size_t)(e0 + em) * 4];
    const float s0 = sh4.x, sx = sh4.y, sy = sh4.z, sz = sh4.w;

    __syncthreads();   // (B) sG complete

    // ---- F features in f32: crew0 builds F0, crew1 builds F1 (wave-local rows, no barrier) ----
    {
        const float* x = sG + em * 56;
        const float c0S = s0 * A_SCAL;
        const float c0V = s0 * A_VEC;
        const float cD3 = INV_SQRT3 * A_SCAL;
        const float cC2 = INV_SQRT2 * A_VEC;
        if (half == 0) {
            float* F = sF0 + em * 61;
            #pragma unroll
            for (int t = 0; t < 4; t++) {
                int u = quad * 4 + t;
                float x0e = x[u];
                F[u]      = x0e * c0S;    // wA0
                F[20 + u] = x0e * A_VEC;  // wA1
            }
            {
                int u = quad;
                float a0 = x[16 + u*3], a1 = x[16 + u*3 + 1], a2 = x[16 + u*3 + 2]; // x1o
                float b0 = x[28 + u*3], b1 = x[28 + u*3 + 1], b2 = x[28 + u*3 + 2]; // x1e
                F[16 + u] = (a0*sx + a1*sy + a2*sz) * cD3;        // wB0 dot_b
                F[36 + u*3 + 0] = a0 * c0V;                       // wB1
                F[36 + u*3 + 1] = a1 * c0V;
                F[36 + u*3 + 2] = a2 * c0V;
                F[48 + u*3 + 0] = (b1*sz - b2*sy) * cC2;          // wC1 cross(x1e,s1)  [..59]
                F[48 + u*3 + 1] = (b2*sx - b0*sz) * cC2;
                F[48 + u*3 + 2] = (b0*sy - b1*sx) * cC2;
            }
        } else {
            float* F = sF1 + em * 61;
            {
                int u = quad;
                float a0 = x[16 + u*3], a1 = x[16 + u*3 + 1], a2 = x[16 + u*3 + 2]; // x1o
                float b0 = x[28 + u*3], b1 = x[28 + u*3 + 1], b2 = x[28 + u*3 + 2]; // x1e
                F[u*3 + 0]      = (a1*sz - a2*sy) * cC2;          // wB1e cross(x1o,s1)
                F[u*3 + 1]      = (a2*sx - a0*sz) * cC2;
                F[u*3 + 2]      = (a0*sy - a1*sx) * cC2;
                F[12 + u*3 + 0] = b0 * c0V;                       // wC1e
                F[12 + u*3 + 1] = b1 * c0V;
                F[12 + u*3 + 2] = b2 * c0V;
                F[40 + u]       = (b0*sx + b1*sy + b2*sz) * cD3;  // wC0o dot_c
            }
            #pragma unroll
            for (int t = 0; t < 4; t++) {
                int u = quad * 4 + t;
                float x0o = x[40 + u];
                F[24 + u] = x0o * A_VEC;  // wD1e
                F[44 + u] = x0o * c0S;    // wD0o  [..59]
            }
        }
    }

    const unsigned short* Wt = W2L + (size_t)half * 26 * 1024;  // this crew's 26 tiles (L2-hot)

    // ---- crew0 preloads edge_attr -> bf16 regs + GEMM1 ----
    bf16x8 hb0, hb1;
    if (half == 0) {
        const float* arow = edge_attr + (size_t)(e0 + em) * EF;
        float av0[8], av1[8];
        {
            float4 p0 = *(const float4*)(arow + quad * 8);
            float4 p1 = *(const float4*)(arow + quad * 8 + 4);
            av0[0]=p0.x; av0[1]=p0.y; av0[2]=p0.z; av0[3]=p0.w;
            av0[4]=p1.x; av0[5]=p1.y; av0[6]=p1.z; av0[7]=p1.w;
        }
        if (quad < 2) {
            float4 p0 = *(const float4*)(arow + 32 + quad * 8);
            float4 p1 = *(const float4*)(arow + 32 + quad * 8 + 4);
            av1[0]=p0.x; av1[1]=p0.y; av1[2]=p0.z; av1[3]=p0.w;
            av1[4]=p1.x; av1[5]=p1.y; av1[6]=p1.z; av1[7]=p1.w;
        } else {
            #pragma unroll
            for (int j = 0; j < 8; j++) av1[j] = 0.f;
            if (quad == 2) av1[0] = 1.f;           // bias row k=48
        }
        u16x8 ub0, ub1;
        #pragma unroll
        for (int j = 0; j < 8; j++) { ub0[j] = f2bf(av0[j]); ub1[j] = f2bf(av1[j]); }
        hb0 = __builtin_bit_cast(bf16x8, ub0);
        hb1 = __builtin_bit_cast(bf16x8, ub1);

        // ---- GEMM1 (crew0 only): H[e][hid] -> sH ----
        #pragma unroll
        for (int nth = 0; nth < 3; nth++) {
            bf16x8 a0 = __builtin_bit_cast(bf16x8, *(const u16x8*)&W1T[(nth*16 + m)*64 + quad*8]);
            bf16x8 a1 = __builtin_bit_cast(bf16x8, *(const u16x8*)&W1T[(nth*16 + m)*64 + 32 + quad*8]);
            f32x4 c = {0.f, 0.f, 0.f, 0.f};
            c = __builtin_amdgcn_mfma_f32_16x16x32_bf16(a0, hb0, c, 0, 0, 0);
            c = __builtin_amdgcn_mfma_f32_16x16x32_bf16(a1, hb1, c, 0, 0, 0);
            u16x4 hp;
            #pragma unroll
            for (int r = 0; r < 4; r++) hp[r] = f2bf(fmaxf(c[r], 0.f));
            *(u16x4*)&sH[em * 72 + nth*16 + quad*4] = hp;
        }
        if (quad == 3) {
            u16x4 b = {0x3F80, 0, 0, 0}, z = {0, 0, 0, 0};
            *(u16x4*)&sH[em * 72 + 48] = b;
            *(u16x4*)&sH[em * 72 + 52] = z;
            *(u16x4*)&sH[em * 72 + 56] = z;
            *(u16x4*)&sH[em * 72 + 60] = z;
        }
    }

    // ---- prime the W2 register ring (6 tiles deep, 12 loads in flight, ~48 VGPR) ----
    // Latency overlaps GEMM1 (crew0) / arrives-early idle (crew1) + barrier (D).
    u16x8 AFr[6], BFr[6];
    #pragma unroll
    for (int p = 0; p < 6; p++) {
        AFr[p] = *(const u16x8*)&Wt[p * 1024 + lane * 8];
        BFr[p] = *(const u16x8*)&Wt[p * 1024 + 512 + lane * 8];
    }

    __syncthreads();   // (D) sH visible to all waves

    bf16x8 HB0 = __builtin_bit_cast(bf16x8, *(const u16x8*)&sH[em * 72 + quad*8]);
    bf16x8 HB1 = __builtin_bit_cast(bf16x8, *(const u16x8*)&sH[em * 72 + 32 + quad*8]);
    const float inv = sInv[em];
    float* orow = out + (size_t)sSrc[em] * IRR;

    if (half == 0) {
        const float* Fp = sF0 + em * 61;
        // ---- tiles 0..25: o0e (ch 0..15) + o1o (ch 16..27) ----
        float oe[4] = {0.f,0.f,0.f,0.f};
        float sA[4] = {0.f,0.f,0.f,0.f};
        float t1[12] = {0.f,0.f,0.f,0.f,0.f,0.f,0.f,0.f,0.f,0.f,0.f,0.f};
        #pragma unroll
        for (int i = 0; i < 26; i++) {
            u16x8 Af = AFr[i % 6];
            u16x8 Bf = BFr[i % 6];
            if (i + 6 < 26) {       // refill ring slot with tile i+6 (static idx under unroll)
                AFr[i % 6] = *(const u16x8*)&Wt[(i + 6) * 1024 + lane * 8];
                BFr[i % 6] = *(const u16x8*)&Wt[(i + 6) * 1024 + 512 + lane * 8];
            }
            f32x4 c = {0.f,0.f,0.f,0.f};
            c = __builtin_amdgcn_mfma_f32_16x16x32_bf16(__builtin_bit_cast(bf16x8, Af), HB0, c, 0, 0, 0);
            c = __builtin_amdgcn_mfma_f32_16x16x32_bf16(__builtin_bit_cast(bf16x8, Bf), HB1, c, 0, 0, 0);
            if (i < 20) {
                float f = Fp[i];
                #pragma unroll
                for (int r = 0; r < 4; r++) oe[r] += f * c[r];
            } else if (i < 24) {
                float f = Fp[20 + (i - 20)*4 + quad];
                #pragma unroll
                for (int r = 0; r < 4; r++) sA[r] += f * c[r];
            } else {
                int u = (i - 24)*4 + quad;
                #pragma unroll
                for (int i3 = 0; i3 < 3; i3++) {
                    float f = Fp[36 + u*3 + i3];
                    #pragma unroll
                    for (int r = 0; r < 4; r++) t1[i3*4 + r] += f * c[r];
                }
            }
        }
        #pragma unroll
        for (int r = 0; r < 4; r++) {
            sA[r] += __shfl_xor(sA[r], 16, 64);  sA[r] += __shfl_xor(sA[r], 32, 64);
        }
        #pragma unroll
        for (int i = 0; i < 12; i++) {
            t1[i] += __shfl_xor(t1[i], 16, 64);  t1[i] += __shfl_xor(t1[i], 32, 64);
        }
        // ---- direct atomic scatter from registers ----
        #pragma unroll
        for (int r = 0; r < 4; r++)
            unsafeAtomicAdd(&orow[quad*4 + r], oe[r] * inv);    // ch 0..15
        #pragma unroll
        for (int q = 0; q < 4; q++) if (quad == q) {            // ch 16..27 (quad q -> group q)
            unsafeAtomicAdd(&orow[16 + q*3 + 0], (sA[q]*sx + t1[0*4 + q]) * inv);
            unsafeAtomicAdd(&orow[16 + q*3 + 1], (sA[q]*sy + t1[1*4 + q]) * inv);
            unsafeAtomicAdd(&orow[16 + q*3 + 2], (sA[q]*sz + t1[2*4 + q]) * inv);
        }
    } else {
        const float* Fp = sF1 + em * 61;
        // ---- tiles 26..51: o1e (ch 28..39) + o0o (ch 40..55) ----
        float sD[4] = {0.f,0.f,0.f,0.f};
        float t1[12] = {0.f,0.f,0.f,0.f,0.f,0.f,0.f,0.f,0.f,0.f,0.f,0.f};
        float oo[4] = {0.f,0.f,0.f,0.f};
        #pragma unroll
        for (int i = 0; i < 26; i++) {
            u16x8 Af = AFr[i % 6];
            u16x8 Bf = BFr[i % 6];
            if (i + 6 < 26) {
                AFr[i % 6] = *(const u16x8*)&Wt[(i + 6) * 1024 + lane * 8];
                BFr[i % 6] = *(const u16x8*)&Wt[(i + 6) * 1024 + 512 + lane * 8];
            }
            f32x4 c = {0.f,0.f,0.f,0.f};
            c = __builtin_amdgcn_mfma_f32_16x16x32_bf16(__builtin_bit_cast(bf16x8, Af), HB0, c, 0, 0, 0);
            c = __builtin_amdgcn_mfma_f32_16x16x32_bf16(__builtin_bit_cast(bf16x8, Bf), HB1, c, 0, 0, 0);
            if (i < 2) {
                int j = i*4 + quad;
                #pragma unroll
                for (int i3 = 0; i3 < 3; i3++) {
                    float f = Fp[j*3 + i3];
                    #pragma unroll
                    for (int r = 0; r < 4; r++) t1[i3*4 + r] += f * c[r];
                }
            } else if (i < 6) {
                float f = Fp[24 + (i - 2)*4 + quad];
                #pragma unroll
                for (int r = 0; r < 4; r++) sD[r] += f * c[r];
            } else {
                float f = Fp[40 + (i - 6)];
                #pragma unroll
                for (int r = 0; r < 4; r++) oo[r] += f * c[r];
            }
        }
        #pragma unroll
        for (int r = 0; r < 4; r++) {
            sD[r] += __shfl_xor(sD[r], 16, 64);  sD[r] += __shfl_xor(sD[r], 32, 64);
        }
        #pragma unroll
        for (int i = 0; i < 12; i++) {
            t1[i] += __shfl_xor(t1[i], 16, 64);  t1[i] += __shfl_xor(t1[i], 32, 64);
        }
        #pragma unroll
        for (int r = 0; r < 4; r++)
            unsafeAtomicAdd(&orow[40 + quad*4 + r], oo[r] * inv);   // ch 40..55
        #pragma unroll
        for (int q = 0; q < 4; q++) if (quad == q) {                // ch 28..39
            unsafeAtomicAdd(&orow[28 + q*3 + 0], (sD[q]*sx + t1[0*4 + q]) * inv);
            unsafeAtomicAdd(&orow[28 + q*3 + 1], (sD[q]*sy + t1[1*4 + q]) * inv);
            unsafeAtomicAdd(&orow[28 + q*3 + 2], (sD[q]*sz + t1[2*4 + q]) * inv);
        }
    }
}

extern "C" void kernel_launch(void* const* d_in, const int* in_sizes, int n_in,
                              void* d_out, int out_size, void* d_ws, size_t ws_size,
                              hipStream_t stream) {
    const float* node_attr  = (const float*)d_in[0];
    const float* edge_attr  = (const float*)d_in[1];
    const float* edge_sh    = (const float*)d_in[2];
    const float* fc_w1      = (const float*)d_in[3];
    const float* fc_b1      = (const float*)d_in[4];
    const float* fc_w2      = (const float*)d_in[5];
    const float* fc_b2      = (const float*)d_in[6];
    const int*   edge_index = (const int*)d_in[7];

    int* hist = (int*)d_ws;                                    // 8000 ints
    unsigned short* W1T = (unsigned short*)(hist + NNODE);     // 48*64
    unsigned short* W2L = W1T + EF * 64;                       // 52*2*64*8 = 53248

    hipMemsetAsync(hist, 0, NNODE * sizeof(int), stream);
    hipMemsetAsync(d_out, 0, (size_t)out_size * sizeof(float), stream);

    k_setup<<<(NEDGE + 255) / 256, 256, 0, stream>>>(
        fc_w1, fc_b1, fc_w2, fc_b2, W1T, W2L, edge_index, hist);

    tp_fused<<<GRID, NT, 0, stream>>>(node_attr, edge_attr, edge_sh, edge_index,
                                      hist, W1T, W2L, (float*)d_out);
}